// Round 3
// baseline (349.848 us; speedup 1.0000x reference)
//
#include <hip/hip_runtime.h>

typedef _Float16 half8 __attribute__((ext_vector_type(8)));
typedef _Float16 half4v __attribute__((ext_vector_type(4)));
typedef float f32x4 __attribute__((ext_vector_type(4)));

#define ZQ_ELEMS 8388608   // 32*256*32*32
#define N_TOK    32768
#define D_DIM    256
#define K_CB     1024

#define FLAG_CAP 8192      // observed cnt ~730 (deterministic input); 11x margin
#define ESCALE   1024.0f
#define TAU      0.15f     // flag margin (scaled units)
#define FIX_GRID 768

__device__ __align__(16) _Float16 g_eh[K_CB * D_DIM];  // fp16(1024*e)
__device__ __align__(16) float g_ebT[D_DIM * K_CB];    // emb transposed [d][k], 1 MB
__device__ float g_ck[K_CB];                            // 512*||e_k||^2 (prefilter)
__device__ float g_bk[K_CB];                            // f32(sum e^2), np-style B_k
__device__ float g_loss;
__device__ int   g_cnt;
__device__ int   g_fixdone;
__device__ int   g_flags[FLAG_CAP];
__device__ float g_zst[FLAG_CAP * 256];                 // staged z rows (coalesced)
__device__ float g_aA[FLAG_CAP];                        // A_n per flagged token
__device__ unsigned long long g_best[FLAG_CAP];         // (orderedD<<32)|k, atomicMin

__device__ __forceinline__ unsigned long long enc_dk(float D, int k) {
  unsigned int b = __float_as_uint(D);
  unsigned int u = (b & 0x80000000u) ? ~b : (b | 0x80000000u);  // order-preserving
  return (((unsigned long long)u) << 32) | (unsigned int)k;
}

// prep: tables + zero accumulators + reset g_best + emb transpose
__global__ __launch_bounds__(256) void vq_prep(const float* __restrict__ emb) {
  __shared__ float tl[64][65];
  const int tid = threadIdx.x;
  const int w   = tid >> 6;
  const int l   = tid & 63;
  const int k   = (blockIdx.x << 2) + w;          // 256 blocks * 4 waves
  f32x4 v = *(const f32x4*)(emb + (k << 8) + (l << 2));
  double sd = (double)v[0]*v[0] + (double)v[1]*v[1] + (double)v[2]*v[2] + (double)v[3]*v[3];
  #pragma unroll
  for (int m = 1; m < 64; m <<= 1) sd += __shfl_xor(sd, m);
  if (l == 0) { g_bk[k] = (float)sd; g_ck[k] = 512.0f * (float)sd; }
  half4v h;
  h[0] = (_Float16)(v[0] * ESCALE); h[1] = (_Float16)(v[1] * ESCALE);
  h[2] = (_Float16)(v[2] * ESCALE); h[3] = (_Float16)(v[3] * ESCALE);
  *(half4v*)(g_eh + (k << 8) + (l << 2)) = h;
  const int gi = blockIdx.x * 256 + tid;
  if (gi < FLAG_CAP) g_best[gi] = ~0ULL;
  if (blockIdx.x == 0 && tid == 0) { g_loss = 0.0f; g_cnt = 0; g_fixdone = 0; }
  // transpose tile (blocks 0..63): emb [k][d] -> g_ebT [d][k]
  if (blockIdx.x < 64) {
    const int tx = tid & 63, ty = tid >> 6;
    const int k0 = (blockIdx.x & 15) << 6;
    const int d0 = (blockIdx.x >> 4) << 6;
    #pragma unroll
    for (int j = 0; j < 16; j++) {
      const int kk = (ty << 4) + j;
      tl[kk][tx] = emb[((k0 + kk) << 8) + d0 + tx];
    }
    __syncthreads();
    #pragma unroll
    for (int j = 0; j < 16; j++) {
      const int dd = (ty << 4) + j;
      g_ebT[((d0 + dd) << 10) + k0 + tx] = tl[tx][dd];
    }
  }
}

// main: 64 tokens/block, 8 waves each owning 1/8 of K with the round-0 inner
// body (single k-tile per jj, acc[4] live only). 512 blocks x 512 thr ->
// 2 blocks/CU = 16 waves/CU. Same per-block traffic as round 0, 2x concurrency.
__global__ __launch_bounds__(512, 4) void vq_main(const float* __restrict__ x,
                                                  const float* __restrict__ emb,
                                                  float* __restrict__ out) {
  __shared__ __align__(16) _Float16 zt[64 * 256];   // 32 KB, XOR-swizzled
  __shared__ float ckl[K_CB];                        // 4 KB; reused as zl in staging
  __shared__ float wv1[8][64], wv2[8][64];
  __shared__ int   wi1[8][64];
  __shared__ int   fidx[64];
  __shared__ float lred[8];
  __shared__ int   fcnt;
  __shared__ int   fslot[64], ftok[64];

  const int tid = threadIdx.x;
  const int n0  = blockIdx.x << 6;
  const int b   = blockIdx.x >> 4;
  const int hw0 = (blockIdx.x & 15) << 6;

  if (tid == 0) fcnt = 0;
  ckl[tid] = g_ck[tid];
  ckl[tid + 512] = g_ck[tid + 512];

  // stage x tile -> fp16; (n,d) lives at n*256 + (((d>>3)^(n&7)^(n>>3))<<3) + (d&7)
  {
    const int hw8 = (tid & 7) << 3;
    const int dl  = tid >> 3;               // 0..63
    #pragma unroll
    for (int it = 0; it < 4; it++) {
      const int d = (it << 6) + dl;
      const float* src = x + (((b << 8) + d) << 10) + hw0 + hw8;
      f32x4 a0 = *(const f32x4*)src;
      f32x4 a1 = *(const f32x4*)(src + 4);
      _Float16 cv[8];
      cv[0]=(_Float16)a0[0]; cv[1]=(_Float16)a0[1]; cv[2]=(_Float16)a0[2]; cv[3]=(_Float16)a0[3];
      cv[4]=(_Float16)a1[0]; cv[5]=(_Float16)a1[1]; cv[6]=(_Float16)a1[2]; cv[7]=(_Float16)a1[3];
      const int blkx = d >> 3;
      #pragma unroll
      for (int i = 0; i < 8; i++) {
        const int n   = hw8 + i;                    // n&7 = i, n>>3 = tid&7
        const int blk = blkx ^ i ^ (tid & 7);
        zt[(n << 8) + (blk << 3) + (d & 7)] = cv[i];
      }
    }
  }
  __syncthreads();

  const int w = tid >> 6;                   // 0..7
  const int l = tid & 63;
  const int c = l & 15;
  const int q = l >> 4;

  float v1[4][4], v2[4][4]; int i1[4][4];
  #pragma unroll
  for (int t = 0; t < 4; t++)
    #pragma unroll
    for (int r = 0; r < 4; r++) { v1[t][r] = -3e38f; v2[t][r] = -3e38f; i1[t][r] = 0; }

  // K loop: wave w owns k = w*16 + jj*128 + c  (8 jj, single k-tile per pass)
  for (int jj = 0; jj < 8; jj++) {
    const int k0 = (w << 4) + (jj << 7);
    const int kk = k0 + c;
    const float ckv = ckl[kk];
    f32x4 acc[4];
    #pragma unroll
    for (int t = 0; t < 4; t++) acc[t] = f32x4{-ckv, -ckv, -ckv, -ckv};
    #pragma unroll
    for (int s = 0; s < 8; s++) {
      const half8 bf = *(const half8*)(g_eh + (kk << 8) + (s << 5) + (q << 3));
      #pragma unroll
      for (int t = 0; t < 4; t++) {
        const int n  = (t << 4) + c;
        const int sw = (n & 7) ^ (n >> 3);
        const half8 a = *(const half8*)(zt + (n << 8) + ((((s << 2) + q) ^ sw) << 3));
        acc[t] = __builtin_amdgcn_mfma_f32_16x16x32_f16(a, bf, acc[t], 0, 0, 0);
      }
    }
    #pragma unroll
    for (int t = 0; t < 4; t++)
      #pragma unroll
      for (int r = 0; r < 4; r++) {
        const float sv = acc[t][r];
        if (sv > v1[t][r]) { v2[t][r] = v1[t][r]; v1[t][r] = sv; i1[t][r] = kk; }
        else if (sv > v2[t][r]) v2[t][r] = sv;
      }
  }

  // top-2 merge across the 16 column lanes, then across 8 waves
  #pragma unroll
  for (int t = 0; t < 4; t++)
    #pragma unroll
    for (int r = 0; r < 4; r++) {
      float a1v = v1[t][r], a2v = v2[t][r]; int ai = i1[t][r];
      #pragma unroll
      for (int m = 8; m >= 1; m >>= 1) {
        const float o1 = __shfl_xor(a1v, m);
        const int   oi = __shfl_xor(ai, m);
        const float o2 = __shfl_xor(a2v, m);
        if (o1 > a1v || (o1 == a1v && oi < ai)) { a2v = fmaxf(a1v, o2); a1v = o1; ai = oi; }
        else a2v = fmaxf(a2v, o1);
      }
      if (c == 0) {
        const int nl = (t << 4) + (q << 2) + r;
        wv1[w][nl] = a1v; wv2[w][nl] = a2v; wi1[w][nl] = ai;
      }
    }
  __syncthreads();

  if (tid < 64) {
    float a1v = wv1[0][tid], a2v = wv2[0][tid]; int ai = wi1[0][tid];
    #pragma unroll
    for (int ww = 1; ww < 8; ww++) {
      const float o1 = wv1[ww][tid]; const int oi = wi1[ww][tid]; const float o2 = wv2[ww][tid];
      if (o1 > a1v || (o1 == a1v && oi < ai)) { a2v = fmaxf(a1v, o2); a1v = o1; ai = oi; }
      else a2v = fmaxf(a2v, o1);
    }
    fidx[tid] = ai;
    out[ZQ_ELEMS + n0 + tid] = (float)ai;        // idx as f32
    if (a1v - a2v < TAU) {                       // ambiguous -> np-replicated pass 2
      int p = atomicAdd(&g_cnt, 1);
      if (p < FLAG_CAP) {
        g_flags[p] = n0 + tid;
        int lp = atomicAdd(&fcnt, 1);
        fslot[lp] = p; ftok[lp] = n0 + tid;
      }
    }
  }
  __syncthreads();

  // gather e[idx] (f32), write z_quant f32 (coalesced over hw), accumulate loss
  float lacc = 0.0f;
  {
    const int hw = tid & 63;
    const int g  = tid >> 6;                     // 0..7; groups own disjoint dblk
    const int sw = (hw & 7) ^ (hw >> 3);
    const float* erow = emb + (fidx[hw] << 8);
    #pragma unroll
    for (int it = 0; it < 4; it++) {
      const int dblk = (it << 3) + g;            // 0..31
      half8 zv = *(const half8*)(zt + (hw << 8) + ((dblk ^ sw) << 3));
      f32x4 e0 = *(const f32x4*)(erow + (dblk << 3));
      f32x4 e1 = *(const f32x4*)(erow + (dblk << 3) + 4);
      #pragma unroll
      for (int j = 0; j < 8; j++) {
        const int d = (dblk << 3) + j;
        const float ef = (j < 4) ? e0[j] : e1[j - 4];
        const float df = ef - (float)zv[j];
        lacc += df * df;
        out[(((b << 8) + d) << 10) + hw0 + hw] = ef;
      }
    }
  }
  #pragma unroll
  for (int m = 1; m < 64; m <<= 1) lacc += __shfl_xor(lacc, m);
  if (l == 0) lred[w] = lacc;
  __syncthreads();
  if (tid == 0) {
    float ls = 0.0f;
    #pragma unroll
    for (int i = 0; i < 8; i++) ls += lred[i];
    atomicAdd(&g_loss, ls);
  }

  // inline staging of this block's flagged tokens: exact f32 x re-read ->
  // coalesced g_zst row; A_n with the SAME f64 op order as pass 2.
  const int nf = fcnt;
  for (int f = 0; f < nf; f++) {
    const int s = fslot[f];
    const int n = ftok[f];
    const int bb = n >> 10, hw = n & 1023;
    if (tid < 256) {
      const float zv = x[(((bb << 8) + tid) << 10) + hw];
      g_zst[(s << 8) + tid] = zv;
      ckl[tid] = zv;                             // ckl reused as zl
    }
    __syncthreads();
    if (tid < 32) {
      double sa = 0.0;
      #pragma unroll
      for (int j = 0; j < 8; j++) { const double z = (double)ckl[(tid << 3) + j]; sa += z * z; }
      #pragma unroll
      for (int m = 1; m < 32; m <<= 1) sa += __shfl_xor(sa, m);
      if (tid == 0) g_aA[s] = (float)sa;
    }
    __syncthreads();
  }
}

// pass 2: job = (token-quad, r-quarter). Lane owns k = r*256+tid; d-ascending f64
// fma chain (bit-identical D); block tree -> one atomicMin/token. Last block
// decodes winners, fixes changed z_quant rows, writes loss.
__global__ __launch_bounds__(256) void vq_fix(const float* __restrict__ emb,
                                              float* __restrict__ out) {
  __shared__ float zl0[256], zl1[256], zl2[256], zl3[256];
  __shared__ float bvv[4][256];
  __shared__ int   bkk[4][256];
  __shared__ unsigned int chmask[FLAG_CAP / 32];   // 1 KB changed-token bitmap
  __shared__ int   lastflag;
  const int tid = threadIdx.x;
  int cnt = g_cnt; if (cnt > FLAG_CAP) cnt = FLAG_CAP;
  const int njob = ((cnt + 3) >> 2) << 2;
  for (int j = blockIdx.x; j < njob; j += gridDim.x) {
    const int grp = j >> 2, r = j & 3;
    const int s0 = grp << 2;
    const int s1 = (s0 + 1 < cnt) ? s0 + 1 : cnt - 1;
    const int s2 = (s0 + 2 < cnt) ? s0 + 2 : cnt - 1;
    const int s3 = (s0 + 3 < cnt) ? s0 + 3 : cnt - 1;
    zl0[tid] = g_zst[(s0 << 8) + tid];
    zl1[tid] = g_zst[(s1 << 8) + tid];
    zl2[tid] = g_zst[(s2 << 8) + tid];
    zl3[tid] = g_zst[(s3 << 8) + tid];
    __syncthreads();
    double c0 = 0.0, c1 = 0.0, c2 = 0.0, c3 = 0.0;
    const float* colbase = g_ebT + (r << 8) + tid;
    #pragma unroll 8
    for (int d = 0; d < 256; d++) {
      const double e = (double)colbase[d << 10];    // coalesced over tid
      c0 = fma(e, (double)zl0[d], c0);
      c1 = fma(e, (double)zl1[d], c1);
      c2 = fma(e, (double)zl2[d], c2);
      c3 = fma(e, (double)zl3[d], c3);
    }
    const int k = (r << 8) + tid;
    const float bkv = g_bk[k];
    bvv[0][tid] = (g_aA[s0] + bkv) - 2.0f * (float)c0; bkk[0][tid] = k;
    bvv[1][tid] = (g_aA[s1] + bkv) - 2.0f * (float)c1; bkk[1][tid] = k;
    bvv[2][tid] = (g_aA[s2] + bkv) - 2.0f * (float)c2; bkk[2][tid] = k;
    bvv[3][tid] = (g_aA[s3] + bkv) - 2.0f * (float)c3; bkk[3][tid] = k;
    __syncthreads();
    for (int off = 128; off >= 1; off >>= 1) {
      if (tid < off) {
        #pragma unroll
        for (int g = 0; g < 4; g++) {
          const float vc = bvv[g][tid + off]; const int kc = bkk[g][tid + off];
          if (vc < bvv[g][tid] || (vc == bvv[g][tid] && kc < bkk[g][tid])) {
            bvv[g][tid] = vc; bkk[g][tid] = kc;
          }
        }
      }
      __syncthreads();
    }
    if (tid == 0) {
      atomicMin(&g_best[s0], enc_dk(bvv[0][0], bkk[0][0]));
      atomicMin(&g_best[s1], enc_dk(bvv[1][0], bkk[1][0]));
      atomicMin(&g_best[s2], enc_dk(bvv[2][0], bkk[2][0]));
      atomicMin(&g_best[s3], enc_dk(bvv[3][0], bkk[3][0]));
    }
    __syncthreads();
  }

  // last-block finalize (device-scope atomics; g_best re-read atomically)
  __threadfence();
  if (tid == 0) lastflag = (atomicAdd(&g_fixdone, 1) == (int)gridDim.x - 1);
  __syncthreads();
  if (!lastflag) return;
  if (tid == 0) out[ZQ_ELEMS + N_TOK] = g_loss * (1.25f / 8388608.0f);
  for (int i = tid; i < FLAG_CAP / 32; i += 256) chmask[i] = 0u;
  __syncthreads();
  for (int s = tid; s < cnt; s += 256) {
    const int n = g_flags[s];
    const unsigned long long bv = atomicMin(&g_best[s], ~0ULL);  // coherent read
    const int kw = (int)(unsigned int)(bv & 0xFFFFFFFFu);
    const int kold = (int)out[ZQ_ELEMS + n];
    out[ZQ_ELEMS + n] = (float)kw;
    if (kw != kold) {
      g_flags[s] = (int)(((unsigned)n) | ((unsigned)kw << 15) | 0x80000000u);
      atomicOr(&chmask[s >> 5], 1u << (s & 31));
    }
  }
  __syncthreads();
  const int nw = (cnt + 31) >> 5;
  for (int wd = 0; wd < nw; wd++) {
    unsigned int m = chmask[wd];
    while (m) {
      const int bpos = __ffs(m) - 1;
      m &= m - 1;
      const int s = (wd << 5) + bpos;
      const unsigned pv = (unsigned)g_flags[s];    // written by this block, post-barrier
      const int n  = (int)(pv & 0x7FFFu);
      const int kw = (int)((pv >> 15) & 0x3FFu);
      const int bb = n >> 10, hw = n & 1023;
      out[(((bb << 8) + tid) << 10) + hw] = emb[(kw << 8) + tid];
    }
  }
}

extern "C" void kernel_launch(void* const* d_in, const int* in_sizes, int n_in,
                              void* d_out, int out_size, void* d_ws, size_t ws_size,
                              hipStream_t stream) {
  const float* x   = (const float*)d_in[0];
  const float* emb = (const float*)d_in[1];
  float* out = (float*)d_out;
  vq_prep<<<256, 256, 0, stream>>>(emb);
  vq_main<<<512, 512, 0, stream>>>(x, emb, out);
  vq_fix<<<FIX_GRID, 256, 0, stream>>>(emb, out);
}

// Round 4
// 277.016 us; speedup vs baseline: 1.2629x; 1.2629x over previous
//
#include <hip/hip_runtime.h>

typedef _Float16 half8 __attribute__((ext_vector_type(8)));
typedef _Float16 half4v __attribute__((ext_vector_type(4)));
typedef float f32x4 __attribute__((ext_vector_type(4)));

#define ZQ_ELEMS 8388608   // 32*256*32*32
#define N_TOK    32768
#define D_DIM    256
#define K_CB     1024

#define FLAG_CAP 8192      // observed cnt ~730 (deterministic input); 11x margin
#define ESCALE   1024.0f
#define TAU      0.15f     // flag margin (scaled units)
#define FIX_GRID 768

__device__ __align__(16) _Float16 g_eh[K_CB * D_DIM];  // fp16(1024*e)
__device__ __align__(16) float g_ebT[D_DIM * K_CB];    // emb transposed [d][k], 1 MB
__device__ float g_ck[K_CB];                            // 512*||e_k||^2 (prefilter)
__device__ float g_bk[K_CB];                            // f32(sum e^2), np-style B_k
__device__ float g_loss;
__device__ int   g_cnt;
__device__ int   g_fixdone;
__device__ int   g_flags[FLAG_CAP];
__device__ float g_zst[FLAG_CAP * 256];                 // staged z rows (coalesced)
__device__ float g_aA[FLAG_CAP];                        // A_n per flagged token
__device__ unsigned long long g_best[FLAG_CAP];         // (orderedD<<32)|k, atomicMin

__device__ __forceinline__ unsigned long long enc_dk(float D, int k) {
  unsigned int b = __float_as_uint(D);
  unsigned int u = (b & 0x80000000u) ? ~b : (b | 0x80000000u);  // order-preserving
  return (((unsigned long long)u) << 32) | (unsigned int)k;
}

// prep: tables + zero accumulators + reset g_best + emb transpose
__global__ __launch_bounds__(256) void vq_prep(const float* __restrict__ emb) {
  __shared__ float tl[64][65];
  const int tid = threadIdx.x;
  const int w   = tid >> 6;
  const int l   = tid & 63;
  const int k   = (blockIdx.x << 2) + w;          // 256 blocks * 4 waves
  f32x4 v = *(const f32x4*)(emb + (k << 8) + (l << 2));
  double sd = (double)v[0]*v[0] + (double)v[1]*v[1] + (double)v[2]*v[2] + (double)v[3]*v[3];
  #pragma unroll
  for (int m = 1; m < 64; m <<= 1) sd += __shfl_xor(sd, m);
  if (l == 0) { g_bk[k] = (float)sd; g_ck[k] = 512.0f * (float)sd; }
  half4v h;
  h[0] = (_Float16)(v[0] * ESCALE); h[1] = (_Float16)(v[1] * ESCALE);
  h[2] = (_Float16)(v[2] * ESCALE); h[3] = (_Float16)(v[3] * ESCALE);
  *(half4v*)(g_eh + (k << 8) + (l << 2)) = h;
  const int gi = blockIdx.x * 256 + tid;
  if (gi < FLAG_CAP) g_best[gi] = ~0ULL;
  if (blockIdx.x == 0 && tid == 0) { g_loss = 0.0f; g_cnt = 0; g_fixdone = 0; }
  // transpose tile (blocks 0..63): emb [k][d] -> g_ebT [d][k]
  if (blockIdx.x < 64) {
    const int tx = tid & 63, ty = tid >> 6;
    const int k0 = (blockIdx.x & 15) << 6;
    const int d0 = (blockIdx.x >> 4) << 6;
    #pragma unroll
    for (int j = 0; j < 16; j++) {
      const int kk = (ty << 4) + j;
      tl[kk][tx] = emb[((k0 + kk) << 8) + d0 + tx];
    }
    __syncthreads();
    #pragma unroll
    for (int j = 0; j < 16; j++) {
      const int dd = (ty << 4) + j;
      g_ebT[((d0 + dd) << 10) + k0 + tx] = tl[tx][dd];
    }
  }
}

// main: 64 tokens/block, 8 waves, each wave owns 1/8 of K processing 2 k-tiles
// per A-panel pass (halves LDS re-read traffic). __launch_bounds__(512,2):
// hipcc arg2 = min BLOCKS/CU (CUDA semantics, confirmed r0-r3) -> VGPR cap 128,
// 2 blocks/CU = 16 waves/CU guaranteed. Live state ~105 VGPR -> no spill.
__global__ __launch_bounds__(512, 2) void vq_main(const float* __restrict__ x,
                                                  const float* __restrict__ emb,
                                                  float* __restrict__ out) {
  __shared__ __align__(16) _Float16 zt[64 * 256];   // 32 KB, XOR-swizzled
  __shared__ float ckl[K_CB];                        // 4 KB; reused as zl in staging
  __shared__ float wv1[8][64], wv2[8][64];
  __shared__ int   wi1[8][64];
  __shared__ int   fidx[64];
  __shared__ float lred[8];
  __shared__ int   fcnt;
  __shared__ int   fslot[64], ftok[64];

  const int tid = threadIdx.x;
  const int n0  = blockIdx.x << 6;
  const int b   = blockIdx.x >> 4;
  const int hw0 = (blockIdx.x & 15) << 6;

  if (tid == 0) fcnt = 0;
  ckl[tid] = g_ck[tid];
  ckl[tid + 512] = g_ck[tid + 512];

  // stage x tile -> fp16; (n,d) lives at n*256 + (((d>>3)^(n&7)^(n>>3))<<3) + (d&7)
  {
    const int hw8 = (tid & 7) << 3;
    const int dl  = tid >> 3;               // 0..63
    #pragma unroll
    for (int it = 0; it < 4; it++) {
      const int d = (it << 6) + dl;
      const float* src = x + (((b << 8) + d) << 10) + hw0 + hw8;
      f32x4 a0 = *(const f32x4*)src;
      f32x4 a1 = *(const f32x4*)(src + 4);
      _Float16 cv[8];
      cv[0]=(_Float16)a0[0]; cv[1]=(_Float16)a0[1]; cv[2]=(_Float16)a0[2]; cv[3]=(_Float16)a0[3];
      cv[4]=(_Float16)a1[0]; cv[5]=(_Float16)a1[1]; cv[6]=(_Float16)a1[2]; cv[7]=(_Float16)a1[3];
      const int blkx = d >> 3;
      #pragma unroll
      for (int i = 0; i < 8; i++) {
        const int n   = hw8 + i;                    // n&7 = i, n>>3 = tid&7
        const int blk = blkx ^ i ^ (tid & 7);
        zt[(n << 8) + (blk << 3) + (d & 7)] = cv[i];
      }
    }
  }
  __syncthreads();

  const int w = tid >> 6;                   // 0..7
  const int l = tid & 63;
  const int c = l & 15;
  const int q = l >> 4;

  float v1[4][4], v2[4][4]; int i1[4][4];
  #pragma unroll
  for (int t = 0; t < 4; t++)
    #pragma unroll
    for (int r = 0; r < 4; r++) { v1[t][r] = -3e38f; v2[t][r] = -3e38f; i1[t][r] = 0; }

  // K loop: wave w owns k = w*32 + jj*256 + {0,16} + c  (2 k-tiles per A pass)
  for (int jj = 0; jj < 4; jj++) {
    const int k0  = (w << 5) + (jj << 8);
    const int kk0 = k0 + c;
    const int kk1 = kk0 + 16;
    const float ckv0 = ckl[kk0];
    const float ckv1 = ckl[kk1];
    f32x4 acc0[4], acc1[4];
    #pragma unroll
    for (int t = 0; t < 4; t++) {
      acc0[t] = f32x4{-ckv0, -ckv0, -ckv0, -ckv0};
      acc1[t] = f32x4{-ckv1, -ckv1, -ckv1, -ckv1};
    }
    #pragma unroll
    for (int s = 0; s < 8; s++) {
      const half8 bf0 = *(const half8*)(g_eh + (kk0 << 8) + (s << 5) + (q << 3));
      const half8 bf1 = *(const half8*)(g_eh + (kk1 << 8) + (s << 5) + (q << 3));
      #pragma unroll
      for (int t = 0; t < 4; t++) {
        const int n  = (t << 4) + c;
        const int sw = (n & 7) ^ (n >> 3);
        const half8 a = *(const half8*)(zt + (n << 8) + ((((s << 2) + q) ^ sw) << 3));
        acc0[t] = __builtin_amdgcn_mfma_f32_16x16x32_f16(a, bf0, acc0[t], 0, 0, 0);
        acc1[t] = __builtin_amdgcn_mfma_f32_16x16x32_f16(a, bf1, acc1[t], 0, 0, 0);
      }
    }
    #pragma unroll
    for (int t = 0; t < 4; t++)
      #pragma unroll
      for (int r = 0; r < 4; r++) {
        float sv = acc0[t][r];
        if (sv > v1[t][r]) { v2[t][r] = v1[t][r]; v1[t][r] = sv; i1[t][r] = kk0; }
        else if (sv > v2[t][r]) v2[t][r] = sv;
        sv = acc1[t][r];
        if (sv > v1[t][r]) { v2[t][r] = v1[t][r]; v1[t][r] = sv; i1[t][r] = kk1; }
        else if (sv > v2[t][r]) v2[t][r] = sv;
      }
  }

  // top-2 merge across the 16 column lanes, then across 8 waves
  #pragma unroll
  for (int t = 0; t < 4; t++)
    #pragma unroll
    for (int r = 0; r < 4; r++) {
      float a1v = v1[t][r], a2v = v2[t][r]; int ai = i1[t][r];
      #pragma unroll
      for (int m = 8; m >= 1; m >>= 1) {
        const float o1 = __shfl_xor(a1v, m);
        const int   oi = __shfl_xor(ai, m);
        const float o2 = __shfl_xor(a2v, m);
        if (o1 > a1v || (o1 == a1v && oi < ai)) { a2v = fmaxf(a1v, o2); a1v = o1; ai = oi; }
        else a2v = fmaxf(a2v, o1);
      }
      if (c == 0) {
        const int nl = (t << 4) + (q << 2) + r;
        wv1[w][nl] = a1v; wv2[w][nl] = a2v; wi1[w][nl] = ai;
      }
    }
  __syncthreads();

  if (tid < 64) {
    float a1v = wv1[0][tid], a2v = wv2[0][tid]; int ai = wi1[0][tid];
    #pragma unroll
    for (int ww = 1; ww < 8; ww++) {
      const float o1 = wv1[ww][tid]; const int oi = wi1[ww][tid]; const float o2 = wv2[ww][tid];
      if (o1 > a1v || (o1 == a1v && oi < ai)) { a2v = fmaxf(a1v, o2); a1v = o1; ai = oi; }
      else a2v = fmaxf(a2v, o1);
    }
    fidx[tid] = ai;
    out[ZQ_ELEMS + n0 + tid] = (float)ai;        // idx as f32
    if (a1v - a2v < TAU) {                       // ambiguous -> np-replicated pass 2
      int p = atomicAdd(&g_cnt, 1);
      if (p < FLAG_CAP) {
        g_flags[p] = n0 + tid;
        int lp = atomicAdd(&fcnt, 1);
        fslot[lp] = p; ftok[lp] = n0 + tid;
      }
    }
  }
  __syncthreads();

  // gather e[idx] (f32), write z_quant f32 (coalesced over hw), accumulate loss
  float lacc = 0.0f;
  {
    const int hw = tid & 63;
    const int g  = tid >> 6;                     // 0..7; groups own disjoint dblk
    const int sw = (hw & 7) ^ (hw >> 3);
    const float* erow = emb + (fidx[hw] << 8);
    #pragma unroll
    for (int it = 0; it < 4; it++) {
      const int dblk = (it << 3) + g;            // 0..31
      half8 zv = *(const half8*)(zt + (hw << 8) + ((dblk ^ sw) << 3));
      f32x4 e0 = *(const f32x4*)(erow + (dblk << 3));
      f32x4 e1 = *(const f32x4*)(erow + (dblk << 3) + 4);
      #pragma unroll
      for (int j = 0; j < 8; j++) {
        const int d = (dblk << 3) + j;
        const float ef = (j < 4) ? e0[j] : e1[j - 4];
        const float df = ef - (float)zv[j];
        lacc += df * df;
        out[(((b << 8) + d) << 10) + hw0 + hw] = ef;
      }
    }
  }
  #pragma unroll
  for (int m = 1; m < 64; m <<= 1) lacc += __shfl_xor(lacc, m);
  if (l == 0) lred[w] = lacc;
  __syncthreads();
  if (tid == 0) {
    float ls = 0.0f;
    #pragma unroll
    for (int i = 0; i < 8; i++) ls += lred[i];
    atomicAdd(&g_loss, ls);
  }

  // inline staging of this block's flagged tokens: exact f32 x re-read ->
  // coalesced g_zst row; A_n with the SAME f64 op order as pass 2.
  const int nf = fcnt;
  for (int f = 0; f < nf; f++) {
    const int s = fslot[f];
    const int n = ftok[f];
    const int bb = n >> 10, hw = n & 1023;
    if (tid < 256) {
      const float zv = x[(((bb << 8) + tid) << 10) + hw];
      g_zst[(s << 8) + tid] = zv;
      ckl[tid] = zv;                             // ckl reused as zl
    }
    __syncthreads();
    if (tid < 32) {
      double sa = 0.0;
      #pragma unroll
      for (int j = 0; j < 8; j++) { const double z = (double)ckl[(tid << 3) + j]; sa += z * z; }
      #pragma unroll
      for (int m = 1; m < 32; m <<= 1) sa += __shfl_xor(sa, m);
      if (tid == 0) g_aA[s] = (float)sa;
    }
    __syncthreads();
  }
}

// pass 2: job = (token-quad, r-quarter). Lane owns k = r*256+tid; d-ascending f64
// fma chain (bit-identical D); block tree -> one atomicMin/token. Last block
// decodes winners, fixes changed z_quant rows, writes loss.
__global__ __launch_bounds__(256) void vq_fix(const float* __restrict__ emb,
                                              float* __restrict__ out) {
  __shared__ float zl0[256], zl1[256], zl2[256], zl3[256];
  __shared__ float bvv[4][256];
  __shared__ int   bkk[4][256];
  __shared__ unsigned int chmask[FLAG_CAP / 32];   // 1 KB changed-token bitmap
  __shared__ int   lastflag;
  const int tid = threadIdx.x;
  int cnt = g_cnt; if (cnt > FLAG_CAP) cnt = FLAG_CAP;
  const int njob = ((cnt + 3) >> 2) << 2;
  for (int j = blockIdx.x; j < njob; j += gridDim.x) {
    const int grp = j >> 2, r = j & 3;
    const int s0 = grp << 2;
    const int s1 = (s0 + 1 < cnt) ? s0 + 1 : cnt - 1;
    const int s2 = (s0 + 2 < cnt) ? s0 + 2 : cnt - 1;
    const int s3 = (s0 + 3 < cnt) ? s0 + 3 : cnt - 1;
    zl0[tid] = g_zst[(s0 << 8) + tid];
    zl1[tid] = g_zst[(s1 << 8) + tid];
    zl2[tid] = g_zst[(s2 << 8) + tid];
    zl3[tid] = g_zst[(s3 << 8) + tid];
    __syncthreads();
    double c0 = 0.0, c1 = 0.0, c2 = 0.0, c3 = 0.0;
    const float* colbase = g_ebT + (r << 8) + tid;
    #pragma unroll 8
    for (int d = 0; d < 256; d++) {
      const double e = (double)colbase[d << 10];    // coalesced over tid
      c0 = fma(e, (double)zl0[d], c0);
      c1 = fma(e, (double)zl1[d], c1);
      c2 = fma(e, (double)zl2[d], c2);
      c3 = fma(e, (double)zl3[d], c3);
    }
    const int k = (r << 8) + tid;
    const float bkv = g_bk[k];
    bvv[0][tid] = (g_aA[s0] + bkv) - 2.0f * (float)c0; bkk[0][tid] = k;
    bvv[1][tid] = (g_aA[s1] + bkv) - 2.0f * (float)c1; bkk[1][tid] = k;
    bvv[2][tid] = (g_aA[s2] + bkv) - 2.0f * (float)c2; bkk[2][tid] = k;
    bvv[3][tid] = (g_aA[s3] + bkv) - 2.0f * (float)c3; bkk[3][tid] = k;
    __syncthreads();
    for (int off = 128; off >= 1; off >>= 1) {
      if (tid < off) {
        #pragma unroll
        for (int g = 0; g < 4; g++) {
          const float vc = bvv[g][tid + off]; const int kc = bkk[g][tid + off];
          if (vc < bvv[g][tid] || (vc == bvv[g][tid] && kc < bkk[g][tid])) {
            bvv[g][tid] = vc; bkk[g][tid] = kc;
          }
        }
      }
      __syncthreads();
    }
    if (tid == 0) {
      atomicMin(&g_best[s0], enc_dk(bvv[0][0], bkk[0][0]));
      atomicMin(&g_best[s1], enc_dk(bvv[1][0], bkk[1][0]));
      atomicMin(&g_best[s2], enc_dk(bvv[2][0], bkk[2][0]));
      atomicMin(&g_best[s3], enc_dk(bvv[3][0], bkk[3][0]));
    }
    __syncthreads();
  }

  // last-block finalize (device-scope atomics; g_best re-read atomically)
  __threadfence();
  if (tid == 0) lastflag = (atomicAdd(&g_fixdone, 1) == (int)gridDim.x - 1);
  __syncthreads();
  if (!lastflag) return;
  if (tid == 0) out[ZQ_ELEMS + N_TOK] = g_loss * (1.25f / 8388608.0f);
  for (int i = tid; i < FLAG_CAP / 32; i += 256) chmask[i] = 0u;
  __syncthreads();
  for (int s = tid; s < cnt; s += 256) {
    const int n = g_flags[s];
    const unsigned long long bv = atomicMin(&g_best[s], ~0ULL);  // coherent read
    const int kw = (int)(unsigned int)(bv & 0xFFFFFFFFu);
    const int kold = (int)out[ZQ_ELEMS + n];
    out[ZQ_ELEMS + n] = (float)kw;
    if (kw != kold) {
      g_flags[s] = (int)(((unsigned)n) | ((unsigned)kw << 15) | 0x80000000u);
      atomicOr(&chmask[s >> 5], 1u << (s & 31));
    }
  }
  __syncthreads();
  const int nw = (cnt + 31) >> 5;
  for (int wd = 0; wd < nw; wd++) {
    unsigned int m = chmask[wd];
    while (m) {
      const int bpos = __ffs(m) - 1;
      m &= m - 1;
      const int s = (wd << 5) + bpos;
      const unsigned pv = (unsigned)g_flags[s];    // written by this block, post-barrier
      const int n  = (int)(pv & 0x7FFFu);
      const int kw = (int)((pv >> 15) & 0x3FFu);
      const int bb = n >> 10, hw = n & 1023;
      out[(((bb << 8) + tid) << 10) + hw] = emb[(kw << 8) + tid];
    }
  }
}

extern "C" void kernel_launch(void* const* d_in, const int* in_sizes, int n_in,
                              void* d_out, int out_size, void* d_ws, size_t ws_size,
                              hipStream_t stream) {
  const float* x   = (const float*)d_in[0];
  const float* emb = (const float*)d_in[1];
  float* out = (float*)d_out;
  vq_prep<<<256, 256, 0, stream>>>(emb);
  vq_main<<<512, 512, 0, stream>>>(x, emb, out);
  vq_fix<<<FIX_GRID, 256, 0, stream>>>(emb, out);
}